// Round 6
// baseline (606.193 us; speedup 1.0000x reference)
//
#include <hip/hip_runtime.h>
#include <hip/hip_bf16.h>

// NATLayer fp32 I/O, bf16 internal. B=8, H=W=128, C=128, HEADS=4, d=32, K=7,
// N=16384 (1-D neighborhood over flattened N), M = B*N = 131072.
//
// Round 6: conflict-correct swizzle (stride 128/256 shorts, key row&7) +
// 3 blocks/CU occupancy for both fused kernels.
//  1. K1 (64 tok/block, 53760 B LDS): LN1+QKV+attn+proj+resid(fp32)+LN2
//  2. K3 (64 rows/block, 49152 B LDS): fc1+gelu+fc2(K-halves)+resid -> fp32

#define NPOS 16384
#define MROWS 131072

typedef unsigned short ushort_t;
typedef __bf16 bf8 __attribute__((ext_vector_type(8)));
typedef float f4 __attribute__((ext_vector_type(4)));

#define P_QKV_W 0
#define P_QKV_B 49152
#define P_PROJ_W 49536
#define P_PROJ_B 65920
#define P_FC1_W 66048
#define P_FC1_B 131584
#define P_FC2_W 132096
#define P_FC2_B 197632
#define P_TOTAL 197760

__device__ __forceinline__ float b2f(ushort_t u) {
    union { unsigned int i; float f; } v; v.i = ((unsigned int)u) << 16; return v.f;
}
__device__ __forceinline__ ushort_t f2b(float f) {
    __hip_bfloat16 h = __float2bfloat16(f);
    return *reinterpret_cast<ushort_t*>(&h);
}
// XOR swizzle, 8-short blocks, key=row&7. stride MUST be 128 or 256 shorts
// (row stride == 0 mod 32 banks) -> A-frag b128 reads are 2-way (free).
__device__ __forceinline__ int swz(int row, int col, int stride) {
    return row * stride + ((((col >> 3) ^ (row & 7)) << 3) | (col & 7));
}
__device__ __forceinline__ void ld8(const ushort_t* p, float* d) {
    uint4 pv = *(const uint4*)p;
    const ushort_t* us = (const ushort_t*)&pv;
    #pragma unroll
    for (int e = 0; e < 8; e++) d[e] = b2f(us[e]);
}
__device__ __forceinline__ void st8(ushort_t* p, const float* d) {
    unsigned int pk[4];
    #pragma unroll
    for (int e = 0; e < 4; e++)
        pk[e] = (unsigned int)f2b(d[2 * e]) | ((unsigned int)f2b(d[2 * e + 1]) << 16);
    *(uint4*)p = *(uint4*)pk;
}
__device__ __forceinline__ float fast_gelu(float x) {
    float u = x * (0.7978845608f + 0.0356774081f * x * x);
    float t = 1.0f - 2.0f / (1.0f + __expf(2.0f * u));
    return 0.5f * x * (1.0f + t);
}

__global__ __launch_bounds__(256) void cvt_params(
    const float* __restrict__ qkv_w, const float* __restrict__ qkv_b,
    const float* __restrict__ proj_w, const float* __restrict__ proj_b,
    const float* __restrict__ fc1_w, const float* __restrict__ fc1_b,
    const float* __restrict__ fc2_w, const float* __restrict__ fc2_b,
    ushort_t* __restrict__ p)
{
    int i = blockIdx.x * 256 + threadIdx.x;
    if (i >= P_TOTAL) return;
    float v;
    if      (i < P_QKV_B)  v = qkv_w[i - P_QKV_W];
    else if (i < P_PROJ_W) v = qkv_b[i - P_QKV_B];
    else if (i < P_PROJ_B) v = proj_w[i - P_PROJ_W];
    else if (i < P_FC1_W)  v = proj_b[i - P_PROJ_B];
    else if (i < P_FC1_B)  v = fc1_w[i - P_FC1_W];
    else if (i < P_FC2_W)  v = fc1_b[i - P_FC1_B];
    else if (i < P_FC2_B)  v = fc2_w[i - P_FC2_W];
    else                   v = fc2_b[i - P_FC2_B];
    p[i] = f2b(v);
}

// ======== K1: LN1 + QKV + attention + proj + fp32 residual + LN2 ============
// 64 tokens/block, halo 3 each side -> 70 rows. 512 threads.
// LDS shorts: xs[70][128] swz (8960) | kv[70][256] swz (17920) = 53760 B.
// qo (64x128) overlays xs; ct (64x256-region) overlays kv.
__global__ __launch_bounds__(512, 6) void k1_fused(
    const float* __restrict__ x, const float* __restrict__ n1w,
    const float* __restrict__ n1b, const ushort_t* __restrict__ qkvw,
    const float* __restrict__ qkvb, const float* __restrict__ rpb,
    const ushort_t* __restrict__ projw, const float* __restrict__ projb,
    const float* __restrict__ n2w, const float* __restrict__ n2b,
    ushort_t* __restrict__ x2out, ushort_t* __restrict__ ysout)
{
    extern __shared__ ushort_t sm[];
    ushort_t* xs = sm;            // [70][128] swz; row r = token nl0-3+r
    ushort_t* kv = sm + 8960;     // [70][256] swz; K cols 0..127, V cols 128..255
    ushort_t* qo = sm;            // overlay: [64][128] swz (Q then attn-out)
    ushort_t* ct = sm + 8960;     // overlay: [64] rows x stride 256 swz

    int t0  = blockIdx.x * 64;
    int ib  = t0 & ~(NPOS - 1);
    int nl0 = t0 & (NPOS - 1);
    int tid = threadIdx.x;
    int w = tid >> 6, lane = tid & 63;
    int quad = lane >> 4, lrow = lane & 15;

    // ---- phase 1: LN1 of 70 halo rows (one wave-row per iteration) ----
    {
        int c0 = lane * 2;
        float w0 = n1w[c0], w1 = n1w[c0 + 1];
        float b0 = n1b[c0], b1 = n1b[c0 + 1];
        #pragma unroll
        for (int it = 0; it < 9; it++) {
            int r = it * 8 + w;
            if (r < 70) {
                int nl = min(max(nl0 - 3 + r, 0), NPOS - 1);
                float2 v = *(const float2*)&x[(size_t)(ib + nl) * 128 + c0];
                float s = v.x + v.y, s2 = v.x * v.x + v.y * v.y;
                #pragma unroll
                for (int off = 32; off; off >>= 1) {
                    s  += __shfl_xor(s,  off, 64);
                    s2 += __shfl_xor(s2, off, 64);
                }
                float mu   = s * (1.0f / 128.0f);
                float rstd = rsqrtf(s2 * (1.0f / 128.0f) - mu * mu + 1e-5f);
                float o0 = (v.x - mu) * rstd * w0 + b0;
                float o1 = (v.y - mu) * rstd * w1 + b1;
                unsigned int pk = (unsigned int)f2b(o0) | ((unsigned int)f2b(o1) << 16);
                *(unsigned int*)&xs[swz(r, c0, 128)] = pk;
            }
        }
    }
    __syncthreads();

    // ---- phase 2: QKV GEMM. M-tiles {0,16,32,48,54}, N=384 (3 tiles/wave) ----
    {
        const int MB[5] = {0, 16, 32, 48, 54};
        f4 acc[5][3];
        #pragma unroll
        for (int i = 0; i < 5; i++)
            #pragma unroll
            for (int j = 0; j < 3; j++) { f4 z = {0.f,0.f,0.f,0.f}; acc[i][j] = z; }
        #pragma unroll
        for (int k0 = 0; k0 < 128; k0 += 32) {
            bf8 bv[3];
            #pragma unroll
            for (int jj = 0; jj < 3; jj++) {
                int n = (3 * w + jj) * 16 + lrow;
                bv[jj] = *(const bf8*)&qkvw[(size_t)n * 128 + k0 + quad * 8];
            }
            #pragma unroll
            for (int i = 0; i < 5; i++) {
                bf8 av = *(const bf8*)&xs[swz(MB[i] + lrow, k0 + quad * 8, 128)];
                #pragma unroll
                for (int jj = 0; jj < 3; jj++)
                    acc[i][jj] = __builtin_amdgcn_mfma_f32_16x16x32_bf16(
                        av, bv[jj], acc[i][jj], 0, 0, 0);
            }
        }
        __syncthreads();          // all xs reads done before qo overlay writes
        #pragma unroll
        for (int jj = 0; jj < 3; jj++) {
            int jt = 3 * w + jj;
            int n = jt * 16 + lrow;
            float bj = qkvb[n];
            #pragma unroll
            for (int i = 0; i < 5; i++) {
                #pragma unroll
                for (int rr = 0; rr < 4; rr++) {
                    int mrow = MB[i] + quad * 4 + rr;
                    float v = acc[i][jj][rr] + bj;
                    if (jt < 8) {
                        int t = mrow - 3;
                        if (t >= 0 && t < 64)
                            qo[swz(t, n, 128)] = f2b(v * 0.17677669529663687f);
                    } else {
                        kv[swz(mrow, n - 128, 256)] = f2b(v);
                    }
                }
            }
        }
    }
    __syncthreads();

    // ---- phase 3: attention. thread = (token=tid>>3, head=(tid>>1)&3, half)
    {
        int t = tid >> 3, head = (tid >> 1) & 3, half = tid & 1;
        int n = nl0 + t;
        int s = n - 3;
        if (s < 0) s = 0;
        if (s > NPOS - 7) s = NPOS - 7;
        int r0 = s - nl0 + 3;
        int cb = head * 32 + half * 16;

        float q[16];
        ld8(&qo[swz(t, cb, 128)], q);
        ld8(&qo[swz(t, cb + 8, 128)], q + 8);

        float logit[7];
        #pragma unroll
        for (int j = 0; j < 7; j++) {
            int row = r0 + j;
            float kk[8];
            float p = 0.f;
            ld8(&kv[swz(row, cb, 256)], kk);
            #pragma unroll
            for (int e = 0; e < 8; e++) p += q[e] * kk[e];
            ld8(&kv[swz(row, cb + 8, 256)], kk);
            #pragma unroll
            for (int e = 0; e < 8; e++) p += q[8 + e] * kk[e];
            p += __shfl_xor(p, 1, 64);
            logit[j] = p + rpb[head * 13 + (s + j - n + 6)];
        }
        float m = logit[0];
        #pragma unroll
        for (int j = 1; j < 7; j++) m = fmaxf(m, logit[j]);
        float e[7], esum = 0.f;
        #pragma unroll
        for (int j = 0; j < 7; j++) { e[j] = __expf(logit[j] - m); esum += e[j]; }
        float inv = 1.0f / esum;

        float o[16];
        #pragma unroll
        for (int c = 0; c < 16; c++) o[c] = 0.f;
        #pragma unroll
        for (int j = 0; j < 7; j++) {
            int row = r0 + j;
            float vv[8];
            float ej = e[j];
            ld8(&kv[swz(row, 128 + cb, 256)], vv);
            #pragma unroll
            for (int c = 0; c < 8; c++) o[c] += ej * vv[c];
            ld8(&kv[swz(row, 128 + cb + 8, 256)], vv);
            #pragma unroll
            for (int c = 0; c < 8; c++) o[8 + c] += ej * vv[c];
        }
        #pragma unroll
        for (int c = 0; c < 16; c++) o[c] *= inv;
        st8(&qo[swz(t, cb, 128)], o);
        st8(&qo[swz(t, cb + 8, 128)], o + 8);
    }
    __syncthreads();

    // ---- phase 4: proj (M=64, N=128; wave w owns N-tile w) -> ct ----
    {
        int n = w * 16 + lrow;
        f4 acc2[4];
        #pragma unroll
        for (int i = 0; i < 4; i++) { f4 z = {0.f,0.f,0.f,0.f}; acc2[i] = z; }
        #pragma unroll
        for (int k0 = 0; k0 < 128; k0 += 32) {
            bf8 bv = *(const bf8*)&projw[(size_t)n * 128 + k0 + quad * 8];
            #pragma unroll
            for (int i = 0; i < 4; i++) {
                bf8 av = *(const bf8*)&qo[swz(i * 16 + lrow, k0 + quad * 8, 128)];
                acc2[i] = __builtin_amdgcn_mfma_f32_16x16x32_bf16(av, bv, acc2[i], 0, 0, 0);
            }
        }
        float bj = projb[n];
        #pragma unroll
        for (int i = 0; i < 4; i++) {
            #pragma unroll
            for (int rr = 0; rr < 4; rr++) {
                int row = i * 16 + quad * 4 + rr;
                ct[swz(row, n, 256)] = f2b(acc2[i][rr] + bj);
            }
        }
    }
    __syncthreads();

    // ---- phase 5: + fp32 x residual, LN2, coalesced stores ----
    {
        int c0 = lane * 2;
        float w0 = n2w[c0], w1 = n2w[c0 + 1];
        float b0 = n2b[c0], b1 = n2b[c0 + 1];
        #pragma unroll
        for (int it = 0; it < 8; it++) {
            int t = it * 8 + w;
            unsigned int pv = *(const unsigned int*)&ct[swz(t, c0, 256)];
            float2 xr = *(const float2*)&x[(size_t)(t0 + t) * 128 + c0];
            float v0 = b2f((ushort_t)(pv & 0xffff)) + xr.x;
            float v1 = b2f((ushort_t)(pv >> 16))    + xr.y;
            float s = v0 + v1, s2 = v0 * v0 + v1 * v1;
            #pragma unroll
            for (int off = 32; off; off >>= 1) {
                s  += __shfl_xor(s,  off, 64);
                s2 += __shfl_xor(s2, off, 64);
            }
            float mu   = s * (1.0f / 128.0f);
            float rstd = rsqrtf(s2 * (1.0f / 128.0f) - mu * mu + 1e-5f);
            float o0 = (v0 - mu) * rstd * w0 + b0;
            float o1 = (v1 - mu) * rstd * w1 + b1;
            unsigned int px = (unsigned int)f2b(v0) | ((unsigned int)f2b(v1) << 16);
            unsigned int pk = (unsigned int)f2b(o0) | ((unsigned int)f2b(o1) << 16);
            *(unsigned int*)&x2out[(size_t)(t0 + t) * 128 + c0] = px;
            *(unsigned int*)&ysout[(size_t)(t0 + t) * 128 + c0] = pk;
        }
    }
}

// ======== K3: fc1 + gelu + fc2 (256-wide K-halves) + residual ===============
// 64 rows/block, 512 threads. LDS: ysT[64][128] swz + h[64][256] swz = 49152 B.
__global__ __launch_bounds__(512, 6) void k3_mlp(
    const ushort_t* __restrict__ ys, const ushort_t* __restrict__ fc1w,
    const float* __restrict__ fc1b, const ushort_t* __restrict__ fc2w,
    const float* __restrict__ fc2b, const ushort_t* __restrict__ x2,
    float* __restrict__ out)
{
    extern __shared__ ushort_t sm[];
    ushort_t* ysT = sm;           // [64][128] swz
    ushort_t* h   = sm + 8192;    // [64][256] swz

    int row0 = blockIdx.x * 64;
    int tid = threadIdx.x;
    int w = tid >> 6, lane = tid & 63;
    int quad = lane >> 4, lrow = lane & 15;

    #pragma unroll
    for (int it = 0; it < 2; it++) {
        int qd = it * 512 + tid;
        int r = qd >> 4, lq = qd & 15;
        *(uint4*)&ysT[swz(r, lq * 8, 128)] =
            *(const uint4*)&ys[(size_t)(row0 + r) * 128 + lq * 8];
    }
    __syncthreads();

    f4 acc2[4];
    #pragma unroll
    for (int i = 0; i < 4; i++) { f4 z = {0.f,0.f,0.f,0.f}; acc2[i] = z; }
    int n = w * 16 + lrow;

    for (int hh = 0; hh < 2; hh++) {
        // fc1 half: N=256 local (2 n-tiles/wave), K=128
        f4 acc[4][2];
        #pragma unroll
        for (int i = 0; i < 4; i++)
            #pragma unroll
            for (int j = 0; j < 2; j++) { f4 z = {0.f,0.f,0.f,0.f}; acc[i][j] = z; }
        #pragma unroll
        for (int k0 = 0; k0 < 128; k0 += 32) {
            bf8 bv[2];
            #pragma unroll
            for (int jj = 0; jj < 2; jj++) {
                int frow = hh * 256 + (w * 2 + jj) * 16 + lrow;
                bv[jj] = *(const bf8*)&fc1w[(size_t)frow * 128 + k0 + quad * 8];
            }
            #pragma unroll
            for (int i = 0; i < 4; i++) {
                bf8 av = *(const bf8*)&ysT[swz(i * 16 + lrow, k0 + quad * 8, 128)];
                #pragma unroll
                for (int jj = 0; jj < 2; jj++)
                    acc[i][jj] = __builtin_amdgcn_mfma_f32_16x16x32_bf16(
                        av, bv[jj], acc[i][jj], 0, 0, 0);
            }
        }
        if (hh > 0) __syncthreads();   // prior fc2 finished reading h
        #pragma unroll
        for (int jj = 0; jj < 2; jj++) {
            int cb = (w * 2 + jj) * 16 + lrow;
            float bj = fc1b[hh * 256 + cb];
            #pragma unroll
            for (int i = 0; i < 4; i++) {
                #pragma unroll
                for (int rr = 0; rr < 4; rr++) {
                    int row = i * 16 + quad * 4 + rr;
                    h[swz(row, cb, 256)] = f2b(fast_gelu(acc[i][jj][rr] + bj));
                }
            }
        }
        __syncthreads();
        // fc2 partial over this 256-wide K-half
        #pragma unroll
        for (int k0 = 0; k0 < 256; k0 += 32) {
            bf8 bv = *(const bf8*)&fc2w[(size_t)n * 512 + hh * 256 + k0 + quad * 8];
            #pragma unroll
            for (int i = 0; i < 4; i++) {
                bf8 av = *(const bf8*)&h[swz(i * 16 + lrow, k0 + quad * 8, 256)];
                acc2[i] = __builtin_amdgcn_mfma_f32_16x16x32_bf16(av, bv, acc2[i], 0, 0, 0);
            }
        }
    }

    float bj = fc2b[n];
    #pragma unroll
    for (int i = 0; i < 4; i++) {
        #pragma unroll
        for (int rr = 0; rr < 4; rr++) {
            int grow = row0 + i * 16 + quad * 4 + rr;
            out[(size_t)grow * 128 + n] =
                acc2[i][rr] + bj + b2f(x2[(size_t)grow * 128 + n]);
        }
    }
}

extern "C" void kernel_launch(void* const* d_in, const int* in_sizes, int n_in,
                              void* d_out, int out_size, void* d_ws, size_t ws_size,
                              hipStream_t stream) {
    const float* x      = (const float*)d_in[0];
    const float* n1w    = (const float*)d_in[1];
    const float* n1b    = (const float*)d_in[2];
    const float* qkv_w  = (const float*)d_in[3];
    const float* qkv_b  = (const float*)d_in[4];
    const float* rpb    = (const float*)d_in[5];
    const float* proj_w = (const float*)d_in[6];
    const float* proj_b = (const float*)d_in[7];
    const float* n2w    = (const float*)d_in[8];
    const float* n2b    = (const float*)d_in[9];
    const float* fc1_w  = (const float*)d_in[10];
    const float* fc1_b  = (const float*)d_in[11];
    const float* fc2_w  = (const float*)d_in[12];
    const float* fc2_b  = (const float*)d_in[13];

    ushort_t* ws     = (ushort_t*)d_ws;
    ushort_t* params = ws;                    // [0, 262144)
    ushort_t* x2     = ws + 262144;           // 16.7M elems
    ushort_t* ysb    = ws + 17039360;         // 16.7M elems
    float*    outf   = (float*)d_out;

    cvt_params<<<(P_TOTAL + 255) / 256, 256, 0, stream>>>(
        qkv_w, qkv_b, proj_w, proj_b, fc1_w, fc1_b, fc2_w, fc2_b, params);

    k1_fused<<<MROWS / 64, 512, 53760, stream>>>(
        x, n1w, n1b, params + P_QKV_W, qkv_b, rpb,
        params + P_PROJ_W, proj_b, n2w, n2b, x2, ysb);

    k3_mlp<<<MROWS / 64, 512, 49152, stream>>>(
        ysb, params + P_FC1_W, fc1_b, params + P_FC2_W, fc2_b, x2, outf);
}